// Round 1
// baseline (207.738 us; speedup 1.0000x reference)
//
#include <hip/hip_runtime.h>
#include <math.h>

#define NSEQ 4096
#define LFFT 8192
#define NT   256

// ---------- complex helpers ----------
__device__ __forceinline__ float2 cadd(float2 a, float2 b){ return make_float2(a.x+b.x, a.y+b.y); }
__device__ __forceinline__ float2 csub(float2 a, float2 b){ return make_float2(a.x-b.x, a.y-b.y); }
__device__ __forceinline__ float2 cmul(float2 a, float2 b){
  return make_float2(fmaf(a.x,b.x,-(a.y*b.y)), fmaf(a.x,b.y, a.y*b.x));
}
// a * conj(b)
__device__ __forceinline__ float2 cmulc(float2 a, float2 b){
  return make_float2(fmaf(a.x,b.x, a.y*b.y), fmaf(a.y,b.x,-(a.x*b.y)));
}
// LDS bank-conflict swizzle on float2 index (involution, bijective per 16-block)
__device__ __forceinline__ int swz(int p){ return p ^ ((p>>4)&15); }

// W(k) = exp(-2*pi*i*k/8192), composed from two small tables (k < 8192)
__device__ __forceinline__ float2 twget(const float2* twHi, const float2* twLo, int k){
  return cmul(twHi[k>>6], twLo[k&63]);
}

__device__ __forceinline__ void init_tw(float2* twHi, float2* twLo){
  const float PI2 = 6.28318530717958647692f;
  int tid = threadIdx.x;
  if (tid < 128){
    float ang = -PI2 * (float)(tid*64) / (float)LFFT;
    float s, c; sincosf(ang, &s, &c);
    twHi[tid] = make_float2(c, s);
  } else if (tid < 192){
    int k = tid - 128;
    float ang = -PI2 * (float)k / (float)LFFT;
    float s, c; sincosf(ang, &s, &c);
    twLo[k] = make_float2(c, s);
  }
  __syncthreads();
}

// ---------- radix-4 stages ----------
// Forward DIF stage, sub-FFT length 4H. One barrier at the end.
template<int H>
__device__ __forceinline__ void fwd_r4(float2* z, const float2* twHi, const float2* twLo){
  constexpr int STEP = LFFT/(4*H);
  const int tid = threadIdx.x;
  #pragma unroll
  for (int r = 0; r < LFFT/4/NT; ++r){
    int i = r*NT + tid;                 // butterfly index 0..2047
    int pos = i & (H-1);
    int base = ((i - pos) << 2) + pos;  // (i/H)*4H + pos
    float2 x0 = z[swz(base)];
    float2 x1 = z[swz(base+H)];
    float2 x2 = z[swz(base+2*H)];
    float2 x3 = z[swz(base+3*H)];
    float2 t0 = cadd(x0,x2), t1 = csub(x0,x2);
    float2 t2 = cadd(x1,x3), t3 = csub(x1,x3);
    float2 y0 = cadd(t0,t2);
    float2 y2 = csub(t0,t2);
    float2 y1 = make_float2(t1.x + t3.y, t1.y - t3.x);  // t1 - i*t3
    float2 y3 = make_float2(t1.x - t3.y, t1.y + t3.x);  // t1 + i*t3
    z[swz(base)] = y0;
    if constexpr (H > 1){
      z[swz(base+H)]   = cmul(y1, twget(twHi,twLo,   pos*STEP));
      z[swz(base+2*H)] = cmul(y2, twget(twHi,twLo, 2*pos*STEP));
      z[swz(base+3*H)] = cmul(y3, twget(twHi,twLo, 3*pos*STEP));
    } else {
      z[swz(base+H)]   = y1;
      z[swz(base+2*H)] = y2;
      z[swz(base+3*H)] = y3;
    }
  }
  __syncthreads();
}

// Inverse DIT stage (conjugate twiddles applied on inputs), mirrored order.
template<int H>
__device__ __forceinline__ void inv_r4(float2* z, const float2* twHi, const float2* twLo){
  constexpr int STEP = LFFT/(4*H);
  const int tid = threadIdx.x;
  #pragma unroll
  for (int r = 0; r < LFFT/4/NT; ++r){
    int i = r*NT + tid;
    int pos = i & (H-1);
    int base = ((i - pos) << 2) + pos;
    float2 x0 = z[swz(base)];
    float2 x1, x2, x3;
    if constexpr (H > 1){
      x1 = cmulc(z[swz(base+H)],   twget(twHi,twLo,   pos*STEP));
      x2 = cmulc(z[swz(base+2*H)], twget(twHi,twLo, 2*pos*STEP));
      x3 = cmulc(z[swz(base+3*H)], twget(twHi,twLo, 3*pos*STEP));
    } else {
      x1 = z[swz(base+H)];
      x2 = z[swz(base+2*H)];
      x3 = z[swz(base+3*H)];
    }
    float2 t0 = cadd(x0,x2), t1 = csub(x0,x2);
    float2 t2 = cadd(x1,x3), t3 = csub(x1,x3);
    z[swz(base)]     = cadd(t0,t2);
    z[swz(base+2*H)] = csub(t0,t2);
    z[swz(base+H)]   = make_float2(t1.x - t3.y, t1.y + t3.x);  // t1 + i*t3
    z[swz(base+3*H)] = make_float2(t1.x + t3.y, t1.y - t3.x);  // t1 - i*t3
  }
  __syncthreads();
}

// ---------- kernel A: DynamicPosBias MLP -> a[h][j] ----------
__device__ __forceinline__ void ln_relu16(const float* v, float* y, const float* g, const float* be){
  float mu = 0.f;
  #pragma unroll
  for (int p=0;p<16;++p) mu += v[p];
  mu *= (1.f/16.f);
  float var = 0.f;
  #pragma unroll
  for (int p=0;p<16;++p){ float d = v[p]-mu; var = fmaf(d,d,var); }
  var *= (1.f/16.f);
  float inv = 1.f / sqrtf(var + 1e-5f);
  #pragma unroll
  for (int p=0;p<16;++p){
    float t = fmaf((v[p]-mu)*inv, g[p], be[p]);
    y[p] = t > 0.f ? t : 0.f;
  }
}

__global__ void dpb_kernel(const float* __restrict__ W0, const float* __restrict__ b0,
                           const float* __restrict__ g1, const float* __restrict__ be1,
                           const float* __restrict__ W1, const float* __restrict__ b1,
                           const float* __restrict__ g2, const float* __restrict__ be2,
                           const float* __restrict__ W2, const float* __restrict__ b2,
                           const float* __restrict__ g3, const float* __restrict__ be3,
                           const float* __restrict__ W3, const float* __restrict__ b3,
                           float* __restrict__ a){
  int j = blockIdx.x*NT + threadIdx.x;   // 0..8191
  float t;
  if (j == 0 || j == NSEQ) t = 0.f;
  else if (j < NSEQ)       t = (float)j;
  else                     t = (float)(j - LFFT);   // negative side

  float v[16], y[16];
  #pragma unroll
  for (int p=0;p<16;++p) v[p] = fmaf(t, W0[p], b0[p]);
  ln_relu16(v, y, g1, be1);
  #pragma unroll
  for (int q=0;q<16;++q){ float s=b1[q];
    #pragma unroll
    for (int p=0;p<16;++p) s = fmaf(y[p], W1[p*16+q], s);
    v[q]=s; }
  ln_relu16(v, y, g2, be2);
  #pragma unroll
  for (int q=0;q<16;++q){ float s=b2[q];
    #pragma unroll
    for (int p=0;p<16;++p) s = fmaf(y[p], W2[p*16+q], s);
    v[q]=s; }
  ln_relu16(v, y, g3, be3);
  #pragma unroll
  for (int hh=0;hh<8;++hh){ float s=b3[hh];
    #pragma unroll
    for (int p=0;p<16;++p) s = fmaf(y[p], W3[p*8+hh], s);
    a[hh*LFFT + j] = s; }
}

// ---------- kernel B: forward FFT of a (per head), scrambled order, /L ----------
__global__ __launch_bounds__(NT, 2) void afft_kernel(const float* __restrict__ a,
                                                     float2* __restrict__ Ahat){
  __shared__ float2 z[LFFT];
  __shared__ float2 twHi[128];
  __shared__ float2 twLo[64];
  init_tw(twHi, twLo);
  const int h = blockIdx.x, tid = threadIdx.x;
  const float* ah = a + h*LFFT;
  #pragma unroll
  for (int r = 0; r < LFFT/NT; ++r){
    int j = r*NT + tid;
    z[swz(j)] = make_float2(ah[j], 0.f);
  }
  __syncthreads();
  // radix-2 DIF stage, H = 4096 (full input)
  #pragma unroll
  for (int r = 0; r < LFFT/2/NT; ++r){
    int i = r*NT + tid;
    float2 u = z[swz(i)], v = z[swz(i+NSEQ)];
    z[swz(i)]      = cadd(u, v);
    z[swz(i+NSEQ)] = cmul(csub(u, v), twget(twHi,twLo,i));
  }
  __syncthreads();
  fwd_r4<1024>(z,twHi,twLo); fwd_r4<256>(z,twHi,twLo); fwd_r4<64>(z,twHi,twLo);
  fwd_r4<16>(z,twHi,twLo);   fwd_r4<4>(z,twHi,twLo);   fwd_r4<1>(z,twHi,twLo);
  const float sc = 1.f/(float)LFFT;
  float2* Ah = Ahat + h*LFFT;
  #pragma unroll
  for (int r = 0; r < LFFT/NT; ++r){
    int p = r*NT + tid;
    float2 v = z[swz(p)];
    Ah[p] = make_float2(v.x*sc, v.y*sc);
  }
}

// ---------- kernel C: packed-pair FFT convolution ----------
__global__ __launch_bounds__(NT, 2) void conv_kernel(const float* __restrict__ x,
                                                     const float2* __restrict__ Ahat,
                                                     float* __restrict__ out){
  __shared__ float2 z[LFFT];
  __shared__ float2 twHi[128];
  __shared__ float2 twLo[64];
  init_tw(twHi, twLo);

  // XCD-aware swizzle: 32 e-pair blocks of the same (b,h) land on one XCD
  int bid = blockIdx.x;                       // 0..2047
  int logical = (bid & 7)*256 + (bid >> 3);
  int bh   = logical >> 5;                    // 0..63  (b*8+h)
  int pair = logical & 31;                    // 0..31
  int h    = bh & 7;
  const int tid = threadIdx.x;

  // load two adjacent e-columns as one complex sequence; fuse first radix-2
  // stage (upper half is zero padding): z[i]=v, z[i+4096]=v*W^i
  const float2* xp = (const float2*)x + (size_t)bh*NSEQ*32 + pair;
  #pragma unroll
  for (int r = 0; r < NSEQ/NT; ++r){
    int s = r*NT + tid;
    float2 v = xp[(size_t)s*32];
    z[swz(s)]      = v;
    z[swz(s+NSEQ)] = cmul(v, twget(twHi,twLo,s));
  }
  __syncthreads();

  fwd_r4<1024>(z,twHi,twLo); fwd_r4<256>(z,twHi,twLo); fwd_r4<64>(z,twHi,twLo);
  fwd_r4<16>(z,twHi,twLo);   fwd_r4<4>(z,twHi,twLo);   fwd_r4<1>(z,twHi,twLo);

  // pointwise multiply by scrambled spectrum of a (already /L)
  const float2* Ah = Ahat + h*LFFT;
  #pragma unroll
  for (int r = 0; r < LFFT/NT; ++r){
    int p = r*NT + tid;
    z[swz(p)] = cmul(z[swz(p)], Ah[p]);
  }
  __syncthreads();

  inv_r4<1>(z,twHi,twLo);   inv_r4<4>(z,twHi,twLo);    inv_r4<16>(z,twHi,twLo);
  inv_r4<64>(z,twHi,twLo);  inv_r4<256>(z,twHi,twLo);  inv_r4<1024>(z,twHi,twLo);

  // final inverse radix-2 stage fused with the store (only low half needed)
  float2* op = (float2*)out + (size_t)bh*NSEQ*32 + pair;
  #pragma unroll
  for (int r = 0; r < NSEQ/NT; ++r){
    int i = r*NT + tid;
    float2 u = z[swz(i)];
    float2 v = cmulc(z[swz(i+NSEQ)], twget(twHi,twLo,i));
    op[(size_t)i*32] = cadd(u, v);
  }
}

// ---------- launch ----------
extern "C" void kernel_launch(void* const* d_in, const int* in_sizes, int n_in,
                              void* d_out, int out_size, void* d_ws, size_t ws_size,
                              hipStream_t stream){
  const float* x   = (const float*)d_in[0];
  const float* W0  = (const float*)d_in[1];
  const float* b0  = (const float*)d_in[2];
  const float* g1  = (const float*)d_in[3];
  const float* be1 = (const float*)d_in[4];
  const float* W1  = (const float*)d_in[5];
  const float* b1  = (const float*)d_in[6];
  const float* g2  = (const float*)d_in[7];
  const float* be2 = (const float*)d_in[8];
  const float* W2  = (const float*)d_in[9];
  const float* b2  = (const float*)d_in[10];
  const float* g3  = (const float*)d_in[11];
  const float* be3 = (const float*)d_in[12];
  const float* W3  = (const float*)d_in[13];
  const float* b3  = (const float*)d_in[14];

  float*  a    = (float*)d_ws;                                   // 8*8192 f32 = 256 KB
  float2* Ahat = (float2*)((char*)d_ws + (size_t)8*LFFT*sizeof(float)); // 8*8192 c64 = 512 KB
  float*  outp = (float*)d_out;

  dpb_kernel<<<LFFT/NT, NT, 0, stream>>>(W0,b0,g1,be1,W1,b1,g2,be2,W2,b2,g3,be3,W3,b3, a);
  afft_kernel<<<8, NT, 0, stream>>>(a, Ahat);
  conv_kernel<<<2048, NT, 0, stream>>>(x, Ahat, outp);
}

// Round 2
// 110.638 us; speedup vs baseline: 1.8776x; 1.8776x over previous
//
#include <hip/hip_runtime.h>
#include <math.h>

#define NSEQ 4096
#define LFFT 8192
#define NT   512

// ---------- complex helpers ----------
__device__ __forceinline__ float2 cadd(float2 a, float2 b){ return make_float2(a.x+b.x, a.y+b.y); }
__device__ __forceinline__ float2 csub(float2 a, float2 b){ return make_float2(a.x-b.x, a.y-b.y); }
__device__ __forceinline__ float2 cmul(float2 a, float2 b){
  return make_float2(fmaf(a.x,b.x,-(a.y*b.y)), fmaf(a.x,b.y, a.y*b.x));
}
// a * conj(b)
__device__ __forceinline__ float2 cmulc(float2 a, float2 b){
  return make_float2(fmaf(a.x,b.x, a.y*b.y), fmaf(a.y,b.x,-(a.x*b.y)));
}
#define R8C 0.70710678118654752440f
// z * W8^1 = z * r(1-i)
__device__ __forceinline__ float2 mulW8p1(float2 z){ return make_float2(R8C*(z.x+z.y), R8C*(z.y-z.x)); }
// z * W8^3 = z * (-r)(1+i)
__device__ __forceinline__ float2 mulW8p3(float2 z){ return make_float2(R8C*(z.y-z.x), -R8C*(z.x+z.y)); }
// z * W8^-1 = z * r(1+i)
__device__ __forceinline__ float2 mulW8m1(float2 z){ return make_float2(R8C*(z.x-z.y), R8C*(z.x+z.y)); }
// z * W8^-3 = z * (-r)(1-i)
__device__ __forceinline__ float2 mulW8m3(float2 z){ return make_float2(-R8C*(z.x+z.y), R8C*(z.x-z.y)); }
// z * (-i) ; z * (+i)
__device__ __forceinline__ float2 mulmi(float2 z){ return make_float2( z.y, -z.x); }
__device__ __forceinline__ float2 mulpi(float2 z){ return make_float2(-z.y,  z.x); }

// LDS bank-conflict swizzle on float2 index (involution; b64 floor for all strides used)
__device__ __forceinline__ int swz(int p){ return p ^ ((p>>4)&15); }

// W(k) = exp(-2*pi*i*k/8192), composed from two small tables (k < 8192)
__device__ __forceinline__ float2 twget(const float2* twHi, const float2* twLo, int k){
  return cmul(twHi[k>>6], twLo[k&63]);
}

__device__ __forceinline__ void init_tw(float2* twHi, float2* twLo){
  const float PI2 = 6.28318530717958647692f;
  int tid = threadIdx.x;
  if (tid < 128){
    float ang = -PI2 * (float)(tid*64) / (float)LFFT;
    float s, c; sincosf(ang, &s, &c);
    twHi[tid] = make_float2(c, s);
  } else if (tid < 192){
    int k = tid - 128;
    float ang = -PI2 * (float)k / (float)LFFT;
    float s, c; sincosf(ang, &s, &c);
    twLo[k] = make_float2(c, s);
  }
  __syncthreads();
}

// ---------- radix-8 stages ----------
// Forward DIF stage, sub-FFT length 8H. One barrier at the end.
template<int H>
__device__ __forceinline__ void fwd_r8(float2* z, const float2* twHi, const float2* twLo){
  constexpr int STEP = LFFT/(8*H);
  const int tid = threadIdx.x;
  #pragma unroll
  for (int r = 0; r < LFFT/8/NT; ++r){
    int i = r*NT + tid;                 // butterfly index 0..1023
    int pos = i & (H-1);
    int base = ((i - pos) << 3) + pos;
    float2 x0 = z[swz(base)];
    float2 x1 = z[swz(base+H)];
    float2 x2 = z[swz(base+2*H)];
    float2 x3 = z[swz(base+3*H)];
    float2 x4 = z[swz(base+4*H)];
    float2 x5 = z[swz(base+5*H)];
    float2 x6 = z[swz(base+6*H)];
    float2 x7 = z[swz(base+7*H)];
    float2 e0=cadd(x0,x4), o0=csub(x0,x4);
    float2 e1=cadd(x1,x5), o1=csub(x1,x5);
    float2 e2=cadd(x2,x6), o2=csub(x2,x6);
    float2 e3=cadd(x3,x7), o3=csub(x3,x7);
    // even outputs: 4-DFT of e*
    float2 ta=cadd(e0,e2), tb=csub(e0,e2);
    float2 tc=cadd(e1,e3), td=csub(e1,e3);
    float2 y0=cadd(ta,tc), y4=csub(ta,tc);
    float2 y2=make_float2(tb.x+td.y, tb.y-td.x);   // tb - i*td
    float2 y6=make_float2(tb.x-td.y, tb.y+td.x);   // tb + i*td
    // odd outputs: rotate then 4-DFT
    o1 = mulW8p1(o1); o2 = mulmi(o2); o3 = mulW8p3(o3);
    float2 ua=cadd(o0,o2), ub=csub(o0,o2);
    float2 uc=cadd(o1,o3), ud=csub(o1,o3);
    float2 y1=cadd(ua,uc), y5=csub(ua,uc);
    float2 y3=make_float2(ub.x+ud.y, ub.y-ud.x);   // ub - i*ud
    float2 y7=make_float2(ub.x-ud.y, ub.y+ud.x);   // ub + i*ud
    z[swz(base)] = y0;
    if constexpr (H > 1){
      float2 w1 = twget(twHi,twLo, pos*STEP);
      float2 w2 = cmul(w1,w1);
      float2 w3 = cmul(w2,w1);
      float2 w4 = cmul(w2,w2);
      float2 w5 = cmul(w4,w1);
      float2 w6 = cmul(w4,w2);
      float2 w7 = cmul(w4,w3);
      z[swz(base+H)]   = cmul(y1,w1);
      z[swz(base+2*H)] = cmul(y2,w2);
      z[swz(base+3*H)] = cmul(y3,w3);
      z[swz(base+4*H)] = cmul(y4,w4);
      z[swz(base+5*H)] = cmul(y5,w5);
      z[swz(base+6*H)] = cmul(y6,w6);
      z[swz(base+7*H)] = cmul(y7,w7);
    } else {
      z[swz(base+H)]   = y1;
      z[swz(base+2*H)] = y2;
      z[swz(base+3*H)] = y3;
      z[swz(base+4*H)] = y4;
      z[swz(base+5*H)] = y5;
      z[swz(base+6*H)] = y6;
      z[swz(base+7*H)] = y7;
    }
  }
  __syncthreads();
}

// Inverse DIT stage (conjugate twiddles applied on inputs), mirrored order.
template<int H>
__device__ __forceinline__ void inv_r8(float2* z, const float2* twHi, const float2* twLo){
  constexpr int STEP = LFFT/(8*H);
  const int tid = threadIdx.x;
  #pragma unroll
  for (int r = 0; r < LFFT/8/NT; ++r){
    int i = r*NT + tid;
    int pos = i & (H-1);
    int base = ((i - pos) << 3) + pos;
    float2 x0 = z[swz(base)];
    float2 x1,x2,x3,x4,x5,x6,x7;
    if constexpr (H > 1){
      float2 w1 = twget(twHi,twLo, pos*STEP);
      float2 w2 = cmul(w1,w1);
      float2 w3 = cmul(w2,w1);
      float2 w4 = cmul(w2,w2);
      float2 w5 = cmul(w4,w1);
      float2 w6 = cmul(w4,w2);
      float2 w7 = cmul(w4,w3);
      x1 = cmulc(z[swz(base+H)],   w1);
      x2 = cmulc(z[swz(base+2*H)], w2);
      x3 = cmulc(z[swz(base+3*H)], w3);
      x4 = cmulc(z[swz(base+4*H)], w4);
      x5 = cmulc(z[swz(base+5*H)], w5);
      x6 = cmulc(z[swz(base+6*H)], w6);
      x7 = cmulc(z[swz(base+7*H)], w7);
    } else {
      x1 = z[swz(base+H)];
      x2 = z[swz(base+2*H)];
      x3 = z[swz(base+3*H)];
      x4 = z[swz(base+4*H)];
      x5 = z[swz(base+5*H)];
      x6 = z[swz(base+6*H)];
      x7 = z[swz(base+7*H)];
    }
    float2 e0=cadd(x0,x4), o0=csub(x0,x4);
    float2 e1=cadd(x1,x5), o1=csub(x1,x5);
    float2 e2=cadd(x2,x6), o2=csub(x2,x6);
    float2 e3=cadd(x3,x7), o3=csub(x3,x7);
    float2 ta=cadd(e0,e2), tb=csub(e0,e2);
    float2 tc=cadd(e1,e3), td=csub(e1,e3);
    float2 y0=cadd(ta,tc), y4=csub(ta,tc);
    float2 y2=make_float2(tb.x-td.y, tb.y+td.x);   // tb + i*td
    float2 y6=make_float2(tb.x+td.y, tb.y-td.x);   // tb - i*td
    o1 = mulW8m1(o1); o2 = mulpi(o2); o3 = mulW8m3(o3);
    float2 ua=cadd(o0,o2), ub=csub(o0,o2);
    float2 uc=cadd(o1,o3), ud=csub(o1,o3);
    float2 y1=cadd(ua,uc), y5=csub(ua,uc);
    float2 y3=make_float2(ub.x-ud.y, ub.y+ud.x);   // ub + i*ud
    float2 y7=make_float2(ub.x+ud.y, ub.y-ud.x);   // ub - i*ud
    z[swz(base)]     = y0;
    z[swz(base+H)]   = y1;
    z[swz(base+2*H)] = y2;
    z[swz(base+3*H)] = y3;
    z[swz(base+4*H)] = y4;
    z[swz(base+5*H)] = y5;
    z[swz(base+6*H)] = y6;
    z[swz(base+7*H)] = y7;
  }
  __syncthreads();
}

// ---------- kernel A: DynamicPosBias MLP -> a[h][j] ----------
__device__ __forceinline__ void ln_relu16(const float* v, float* y, const float* g, const float* be){
  float mu = 0.f;
  #pragma unroll
  for (int p=0;p<16;++p) mu += v[p];
  mu *= (1.f/16.f);
  float var = 0.f;
  #pragma unroll
  for (int p=0;p<16;++p){ float d = v[p]-mu; var = fmaf(d,d,var); }
  var *= (1.f/16.f);
  float inv = 1.f / sqrtf(var + 1e-5f);
  #pragma unroll
  for (int p=0;p<16;++p){
    float t = fmaf((v[p]-mu)*inv, g[p], be[p]);
    y[p] = t > 0.f ? t : 0.f;
  }
}

__global__ void dpb_kernel(const float* __restrict__ W0, const float* __restrict__ b0,
                           const float* __restrict__ g1, const float* __restrict__ be1,
                           const float* __restrict__ W1, const float* __restrict__ b1,
                           const float* __restrict__ g2, const float* __restrict__ be2,
                           const float* __restrict__ W2, const float* __restrict__ b2,
                           const float* __restrict__ g3, const float* __restrict__ be3,
                           const float* __restrict__ W3, const float* __restrict__ b3,
                           float* __restrict__ a){
  int j = blockIdx.x*256 + threadIdx.x;   // 0..8191
  float t;
  if (j == 0 || j == NSEQ) t = 0.f;
  else if (j < NSEQ)       t = (float)j;
  else                     t = (float)(j - LFFT);   // negative side

  float v[16], y[16];
  #pragma unroll
  for (int p=0;p<16;++p) v[p] = fmaf(t, W0[p], b0[p]);
  ln_relu16(v, y, g1, be1);
  #pragma unroll
  for (int q=0;q<16;++q){ float s=b1[q];
    #pragma unroll
    for (int p=0;p<16;++p) s = fmaf(y[p], W1[p*16+q], s);
    v[q]=s; }
  ln_relu16(v, y, g2, be2);
  #pragma unroll
  for (int q=0;q<16;++q){ float s=b2[q];
    #pragma unroll
    for (int p=0;p<16;++p) s = fmaf(y[p], W2[p*16+q], s);
    v[q]=s; }
  ln_relu16(v, y, g3, be3);
  #pragma unroll
  for (int hh=0;hh<8;++hh){ float s=b3[hh];
    #pragma unroll
    for (int p=0;p<16;++p) s = fmaf(y[p], W3[p*8+hh], s);
    a[hh*LFFT + j] = s; }
}

// ---------- kernel B: forward FFT of a (per head), scrambled order, /L ----------
__global__ __launch_bounds__(NT, 4) void afft_kernel(const float* __restrict__ a,
                                                     float2* __restrict__ Ahat){
  __shared__ float2 z[LFFT];
  __shared__ float2 twHi[128];
  __shared__ float2 twLo[64];
  init_tw(twHi, twLo);
  const int h = blockIdx.x, tid = threadIdx.x;
  const float* ah = a + h*LFFT;
  #pragma unroll
  for (int r = 0; r < LFFT/NT; ++r){
    int j = r*NT + tid;
    z[swz(j)] = make_float2(ah[j], 0.f);
  }
  __syncthreads();
  // radix-2 DIF stage, full length 8192
  #pragma unroll
  for (int r = 0; r < LFFT/2/NT; ++r){
    int i = r*NT + tid;
    float2 u = z[swz(i)], v = z[swz(i+NSEQ)];
    z[swz(i)]      = cadd(u, v);
    z[swz(i+NSEQ)] = cmul(csub(u, v), twget(twHi,twLo,i));
  }
  __syncthreads();
  fwd_r8<512>(z,twHi,twLo); fwd_r8<64>(z,twHi,twLo);
  fwd_r8<8>(z,twHi,twLo);   fwd_r8<1>(z,twHi,twLo);
  const float sc = 1.f/(float)LFFT;
  float2* Ah = Ahat + h*LFFT;
  #pragma unroll
  for (int r = 0; r < LFFT/NT; ++r){
    int p = r*NT + tid;
    float2 v = z[swz(p)];
    Ah[p] = make_float2(v.x*sc, v.y*sc);
  }
}

// ---------- kernel C: packed-pair FFT convolution ----------
__global__ __launch_bounds__(NT, 4) void conv_kernel(const float* __restrict__ x,
                                                     const float2* __restrict__ Ahat,
                                                     float* __restrict__ out){
  __shared__ float2 z[LFFT];
  __shared__ float2 twHi[128];
  __shared__ float2 twLo[64];
  init_tw(twHi, twLo);

  // XCD-aware swizzle: 32 e-pair blocks of the same (b,h) land on one XCD
  int bid = blockIdx.x;                       // 0..2047
  int logical = (bid & 7)*256 + (bid >> 3);
  int bh   = logical >> 5;                    // 0..63  (b*8+h)
  int pair = logical & 31;                    // 0..31
  int h    = bh & 7;
  const int tid = threadIdx.x;

  // load two adjacent e-columns as one complex sequence; fuse first radix-2
  // stage (upper half is zero padding): z[i]=v, z[i+4096]=v*W^i
  const float2* xp = (const float2*)x + (size_t)bh*NSEQ*32 + pair;
  #pragma unroll
  for (int r = 0; r < NSEQ/NT; ++r){
    int s = r*NT + tid;
    float2 v = xp[(size_t)s*32];
    z[swz(s)]      = v;
    z[swz(s+NSEQ)] = cmul(v, twget(twHi,twLo,s));
  }
  __syncthreads();

  fwd_r8<512>(z,twHi,twLo); fwd_r8<64>(z,twHi,twLo);
  fwd_r8<8>(z,twHi,twLo);   fwd_r8<1>(z,twHi,twLo);

  // pointwise multiply by scrambled spectrum of a (already /L)
  const float2* Ah = Ahat + h*LFFT;
  #pragma unroll
  for (int r = 0; r < LFFT/NT; ++r){
    int p = r*NT + tid;
    z[swz(p)] = cmul(z[swz(p)], Ah[p]);
  }
  __syncthreads();

  inv_r8<1>(z,twHi,twLo);   inv_r8<8>(z,twHi,twLo);
  inv_r8<64>(z,twHi,twLo);  inv_r8<512>(z,twHi,twLo);

  // final inverse radix-2 stage fused with the store (only low half needed)
  float2* op = (float2*)out + (size_t)bh*NSEQ*32 + pair;
  #pragma unroll
  for (int r = 0; r < NSEQ/NT; ++r){
    int i = r*NT + tid;
    float2 u = z[swz(i)];
    float2 v = cmulc(z[swz(i+NSEQ)], twget(twHi,twLo,i));
    op[(size_t)i*32] = cadd(u, v);
  }
}

// ---------- launch ----------
extern "C" void kernel_launch(void* const* d_in, const int* in_sizes, int n_in,
                              void* d_out, int out_size, void* d_ws, size_t ws_size,
                              hipStream_t stream){
  const float* x   = (const float*)d_in[0];
  const float* W0  = (const float*)d_in[1];
  const float* b0  = (const float*)d_in[2];
  const float* g1  = (const float*)d_in[3];
  const float* be1 = (const float*)d_in[4];
  const float* W1  = (const float*)d_in[5];
  const float* b1  = (const float*)d_in[6];
  const float* g2  = (const float*)d_in[7];
  const float* be2 = (const float*)d_in[8];
  const float* W2  = (const float*)d_in[9];
  const float* b2  = (const float*)d_in[10];
  const float* g3  = (const float*)d_in[11];
  const float* be3 = (const float*)d_in[12];
  const float* W3  = (const float*)d_in[13];
  const float* b3  = (const float*)d_in[14];

  float*  a    = (float*)d_ws;                                   // 8*8192 f32 = 256 KB
  float2* Ahat = (float2*)((char*)d_ws + (size_t)8*LFFT*sizeof(float)); // 8*8192 c64 = 512 KB
  float*  outp = (float*)d_out;

  dpb_kernel<<<LFFT/256, 256, 0, stream>>>(W0,b0,g1,be1,W1,b1,g2,be2,W2,b2,g3,be3,W3,b3, a);
  afft_kernel<<<8, NT, 0, stream>>>(a, Ahat);
  conv_kernel<<<2048, NT, 0, stream>>>(x, Ahat, outp);
}